// Round 5
// baseline (891.157 us; speedup 1.0000x reference)
//
#include <hip/hip_runtime.h>

#define NGRAPH 256
#define NNODE  512
#define KNN    6
#define NCAND  12                   // candidate capacity (margin vs bf16 filter error)
#define NF     64
#define ST     68                   // LDS row stride in floats: 272B, 16B-aligned
#define NT     512
#define EXTRA  (NNODE*ST)           // scratch region offset (floats): 34816
#define CANDOFF (EXTRA + 832)       // knn candidates: 512 rows x 12 ushort = 6144 us = 3072 floats
#define LDS_FLOATS (CANDOFF + 3072) // 38720 floats
#define LDS_BYTES  (LDS_FLOATS*4)   // 154880 B (< 160 KiB)
#define BIG 1e30f

typedef float v4f __attribute__((ext_vector_type(4)));
typedef short v8s __attribute__((ext_vector_type(8)));

struct Params {
  const float *x;
  const float *W1,*b1,*a1, *W2,*b2,*a2;
  const float *Wc0,*bc0, *Wc1,*bc1, *Wc2,*bc2, *Wc3,*bc3;
  const float *W3,*b3,*a3, *W4,*b4,*a4;
  const float *Wh1,*bh1, *Wh2,*bh2, *Wh3,*bh3, *Wh4,*bh4;
  float *out;
};

// fp32 -> bf16 (RNE), as raw short
__device__ __forceinline__ short f2bf(float x) {
  union { float f; unsigned u; } cc; cc.f = x;
  unsigned u = cc.u;
  return (short)((u + 0x7FFFu + ((u >> 16) & 1u)) >> 16);
}

// load 8 consecutive fp32 from LDS row, convert to bf16 fragment
__device__ __forceinline__ v8s load_frag(const float* lds, int row, int col0) {
  const float* p = lds + row*ST + col0;
  float4 f0 = *(const float4*)p;
  float4 f1 = *(const float4*)(p + 4);
  v8s a;
  a[0]=f2bf(f0.x); a[1]=f2bf(f0.y); a[2]=f2bf(f0.z); a[3]=f2bf(f0.w);
  a[4]=f2bf(f1.x); a[5]=f2bf(f1.y); a[6]=f2bf(f1.z); a[7]=f2bf(f1.w);
  return a;
}

// 64-feature row GEMM: acc[o] = sum_k row[k]*W[k*64+o].
__device__ __forceinline__ void gemm64(const float* row, const float* W, float* acc) {
#pragma unroll
  for (int o = 0; o < NF; ++o) acc[o] = 0.f;
#pragma unroll 1
  for (int k4 = 0; k4 < 16; ++k4) {
    float4 xv = *(const float4*)(row + 4*k4);
    const float* w = W + 4*k4*NF;
#pragma unroll
    for (int o = 0; o < NF; ++o) acc[o] = fmaf(xv.x, w[o],        acc[o]);
#pragma unroll
    for (int o = 0; o < NF; ++o) acc[o] = fmaf(xv.y, w[NF+o],     acc[o]);
#pragma unroll
    for (int o = 0; o < NF; ++o) acc[o] = fmaf(xv.z, w[2*NF+o],   acc[o]);
#pragma unroll
    for (int o = 0; o < NF; ++o) acc[o] = fmaf(xv.w, w[3*NF+o],   acc[o]);
  }
}

// in-place row linear + PReLU
__device__ __forceinline__ void linear_row(float* lds, int r, const float* W,
                                           const float* b, const float* a) {
  float acc[NF];
  float* row = lds + r*ST;
  gemm64(row, W, acc);
#pragma unroll
  for (int o4 = 0; o4 < 16; ++o4) {
    float t0 = acc[4*o4+0] + b[4*o4+0];
    float t1 = acc[4*o4+1] + b[4*o4+1];
    float t2 = acc[4*o4+2] + b[4*o4+2];
    float t3 = acc[4*o4+3] + b[4*o4+3];
    float4 v;
    v.x = t0 >= 0.f ? t0 : a[4*o4+0]*t0;
    v.y = t1 >= 0.f ? t1 : a[4*o4+1]*t1;
    v.z = t2 >= 0.f ? t2 : a[4*o4+2]*t2;
    v.w = t3 >= 0.f ? t3 : a[4*o4+3]*t3;
    *(float4*)(row + 4*o4) = v;
  }
}

// sorted-ascending top-6 insert; strict <
__device__ __forceinline__ void insert6(float (&b)[6], int (&bi)[6], float v, int vi) {
  if (v < b[5]) {
#pragma unroll
    for (int p = 0; p < 6; ++p) {
      bool lt = v < b[p];
      float tb = b[p]; int ti = bi[p];
      b[p]  = lt ? v  : tb;  bi[p] = lt ? vi : ti;
      v     = lt ? tb : v;   vi    = lt ? ti : vi;
    }
  }
}

// sorted-ascending top-12 insert; strict <
__device__ __forceinline__ void insert12(float (&b)[NCAND], int (&bi)[NCAND], float v, int vi) {
  if (v < b[NCAND-1]) {
#pragma unroll
    for (int p = 0; p < NCAND; ++p) {
      bool lt = v < b[p];
      float tb = b[p]; int ti = bi[p];
      b[p]  = lt ? v  : tb;  bi[p] = lt ? vi : ti;
      v     = lt ? tb : v;   vi    = lt ? ti : vi;
    }
  }
}

__global__ __launch_bounds__(NT, 2) void fused_gnn(Params P) {
  extern __shared__ float lds[];
  unsigned short* cand = (unsigned short*)&lds[CANDOFF];
  const int tid = threadIdx.x;
  const int g   = blockIdx.x;

  // ---- stage x[g] (512x64) into LDS, coalesced float4 ----
  const float4* xg = (const float4*)(P.x + (size_t)g * NNODE * NF);
#pragma unroll 1
  for (int i = tid; i < NNODE*NF/4; i += NT) {
    float4 v = xg[i];
    int row = i >> 4, k4 = i & 15;
    *(float4*)&lds[row*ST + 4*k4] = v;
  }
  __syncthreads();

  const int rA = tid;   // layer-phase / refine row ownership

  // ---- sq[j] = |x_j|^2 into scratch ----
  {
    float s0 = 0.f;
#pragma unroll
    for (int k4 = 0; k4 < 16; ++k4) {
      float4 a = *(const float4*)&lds[rA*ST + 4*k4];
      s0 = fmaf(a.x,a.x,s0); s0 = fmaf(a.y,a.y,s0); s0 = fmaf(a.z,a.z,s0); s0 = fmaf(a.w,a.w,s0);
    }
    lds[EXTRA + rA] = s0;
  }
  __syncthreads();

  // ==== kNN stage 1: bf16 MFMA Gram filter -> top-12 candidates per row ====
  {
    const int lane = tid & 63;
    const int w    = tid >> 6;      // wave 0..7
    const int c    = lane & 15;     // col within tile / frag row selector
    const int qq   = lane >> 4;     // quad 0..3

#pragma unroll 1
    for (int p = 0; p < 4; ++p) {
      const int i0 = (p*8 + w) * 16;          // this wave's 16-row i-tile
      // A fragments (rows i0+c), K=64 via two chained MFMAs
      v8s A0 = load_frag(lds, i0 + c, qq*8);
      v8s A1 = load_frag(lds, i0 + c, 32 + qq*8);

      float dl[4][6]; int il[4][6];
#pragma unroll
      for (int r = 0; r < 4; ++r)
#pragma unroll
        for (int m = 0; m < 6; ++m) { dl[r][m] = BIG; il[r][m] = 0; }

#pragma unroll 1
      for (int jt = 0; jt < 32; ++jt) {
        const int j0 = jt * 16;
        v8s B0 = load_frag(lds, j0 + c, qq*8);
        v8s B1 = load_frag(lds, j0 + c, 32 + qq*8);
        float sqj = lds[EXTRA + j0 + c];
        v4f acc = {0.f, 0.f, 0.f, 0.f};
        acc = __builtin_amdgcn_mfma_f32_16x16x32_bf16(A0, B0, acc, 0, 0, 0);
        acc = __builtin_amdgcn_mfma_f32_16x16x32_bf16(A1, B1, acc, 0, 0, 0);
        const int jj = j0 + c;                 // this lane's j column
#pragma unroll
        for (int r = 0; r < 4; ++r) {
          float e = fmaf(-2.f, acc[r], sqj);
          int irow = i0 + qq*4 + r;            // C layout: row=(lane>>4)*4+reg
          if (jj == irow) e = BIG;             // self-exclusion
          insert6(dl[r], il[r], e, jj);
        }
      }

      // merge per row across the 16 c-lanes (butterfly), capacity 12
#pragma unroll
      for (int r = 0; r < 4; ++r) {
        float cd[NCAND]; int ci[NCAND];
#pragma unroll
        for (int m = 0; m < 6; ++m) { cd[m] = dl[r][m]; ci[m] = il[r][m]; }
#pragma unroll
        for (int m = 6; m < NCAND; ++m) { cd[m] = BIG; ci[m] = 0; }
#pragma unroll
        for (int mask = 1; mask <= 8; mask <<= 1) {
          float pd[NCAND]; int pi[NCAND];
#pragma unroll
          for (int s = 0; s < NCAND; ++s) {
            pd[s] = __shfl_xor(cd[s], mask);
            pi[s] = __shfl_xor(ci[s], mask);
          }
#pragma unroll
          for (int s = 0; s < NCAND; ++s) insert12(cd, ci, pd[s], pi[s]);
        }
        if (c == 0) {
          int irow = i0 + qq*4 + r;
#pragma unroll
          for (int s = 0; s < NCAND; ++s) cand[irow*NCAND + s] = (unsigned short)ci[s];
        }
      }
    }
  }
  __syncthreads();

  // ==== kNN stage 2: exact fp32 re-rank of 12 candidates (R3-identical math) ====
  int nbrA[KNN];
  {
    float4 xr16[16];
#pragma unroll
    for (int k4 = 0; k4 < 16; ++k4)
      xr16[k4] = *(const float4*)&lds[rA*ST + 4*k4];

    float nd[6]; int ni[6];
#pragma unroll
    for (int m = 0; m < 6; ++m) { nd[m] = BIG; ni[m] = 0x7fffffff; }

    int cnd[NCAND];
#pragma unroll
    for (int s = 0; s < NCAND; ++s) cnd[s] = cand[rA*NCAND + s];

#pragma unroll 1
    for (int s = 0; s < NCAND; ++s) {
      int j = cnd[s];
      const float* xj = &lds[j*ST];
      float4 aa = {0.f, 0.f, 0.f, 0.f};
#pragma unroll
      for (int k4 = 0; k4 < 16; ++k4) {
        float4 v = *(const float4*)(xj + 4*k4);
        aa.x = fmaf(xr16[k4].x, v.x, aa.x); aa.y = fmaf(xr16[k4].y, v.y, aa.y);
        aa.z = fmaf(xr16[k4].z, v.z, aa.z); aa.w = fmaf(xr16[k4].w, v.w, aa.w);
      }
      float e = fmaf(-2.f, (aa.x+aa.y)+(aa.z+aa.w), lds[EXTRA + j]);
      // lexicographic (d, idx) insert == np stable top_k
      if (e < nd[5] || (e == nd[5] && j < ni[5])) {
#pragma unroll
        for (int pp = 0; pp < 6; ++pp) {
          bool lt = (e < nd[pp]) || (e == nd[pp] && j < ni[pp]);
          float tb = nd[pp]; int ti = ni[pp];
          nd[pp] = lt ? e : tb;  ni[pp] = lt ? j : ti;
          e      = lt ? tb : e;  j      = lt ? ti : j;
        }
      }
    }
#pragma unroll
    for (int m = 0; m < 6; ++m) nbrA[m] = ni[m];
  }

  // ---- h = prelu(x@W1+b1); h = prelu(h@W2+b2)  (own row, in place) ----
  linear_row(lds, rA, P.W1, P.b1, P.a1);
  linear_row(lds, rA, P.W2, P.b2, P.a2);

  // ---- 4x gconv: out_i = sum_{m in nbr} (h@W)_m + 6b + h_i ----
  const float* Wcs[4] = {P.Wc0, P.Wc1, P.Wc2, P.Wc3};
  const float* bcs[4] = {P.bc0, P.bc1, P.bc2, P.bc3};
#pragma unroll 1
  for (int cv = 0; cv < 4; ++cv) {
    const float* W = Wcs[cv];
    const float* b = bcs[cv];
    // snapshot own h row (own-thread RAW, no barrier needed)
    float hsA[NF];
#pragma unroll
    for (int k4 = 0; k4 < 16; ++k4) {
      float4 v = *(const float4*)&lds[rA*ST + 4*k4];
      hsA[4*k4]=v.x; hsA[4*k4+1]=v.y; hsA[4*k4+2]=v.z; hsA[4*k4+3]=v.w;
    }
    // p = h @ W, published in place
    {
      float p0[NF];
      gemm64(&lds[rA*ST], W, p0);
#pragma unroll
      for (int o4 = 0; o4 < 16; ++o4) {
        float4 v = {p0[4*o4], p0[4*o4+1], p0[4*o4+2], p0[4*o4+3]};
        *(float4*)&lds[rA*ST + 4*o4] = v;
      }
    }
    __syncthreads();                       // all p-rows published
    // gather: s = sum of 6 neighbor p-rows (init from neighbor 0)
    float sA[NF];
    {
      const float* pr = &lds[nbrA[0]*ST];
#pragma unroll
      for (int o4 = 0; o4 < 16; ++o4) {
        float4 v = *(const float4*)(pr + 4*o4);
        sA[4*o4]=v.x; sA[4*o4+1]=v.y; sA[4*o4+2]=v.z; sA[4*o4+3]=v.w;
      }
    }
#pragma unroll
    for (int m = 1; m < KNN; ++m) {
      const float* pr = &lds[nbrA[m]*ST];
#pragma unroll
      for (int o4 = 0; o4 < 16; ++o4) {
        float4 v = *(const float4*)(pr + 4*o4);
        sA[4*o4]+=v.x; sA[4*o4+1]+=v.y; sA[4*o4+2]+=v.z; sA[4*o4+3]+=v.w;
      }
    }
    __syncthreads();                       // all gathers done before overwrite
#pragma unroll
    for (int o4 = 0; o4 < 16; ++o4) {
      float4 v;
      v.x = sA[4*o4]   + 6.f*b[4*o4]   + hsA[4*o4];
      v.y = sA[4*o4+1] + 6.f*b[4*o4+1] + hsA[4*o4+1];
      v.z = sA[4*o4+2] + 6.f*b[4*o4+2] + hsA[4*o4+2];
      v.w = sA[4*o4+3] + 6.f*b[4*o4+3] + hsA[4*o4+3];
      *(float4*)&lds[rA*ST + 4*o4] = v;
    }
  }

  // ---- last two PReLU linears (own row) ----
  linear_row(lds, rA, P.W3, P.b3, P.a3);
  linear_row(lds, rA, P.W4, P.b4, P.a4);

  __syncthreads();   // all h final before pool reads

  // ---- global add pool: pooled[f] = sum_rows h[r][f]; 8 chunks of 64 rows ----
  {
    int f = tid & 63, c = tid >> 6;      // c in 0..7
    int rstart = c * 64;
    float pa=0.f, pb=0.f, pc=0.f, pd=0.f;
#pragma unroll 1
    for (int r = 0; r < 64; r += 4) {
      pa += lds[(rstart+r  )*ST + f];
      pb += lds[(rstart+r+1)*ST + f];
      pc += lds[(rstart+r+2)*ST + f];
      pd += lds[(rstart+r+3)*ST + f];
    }
    lds[EXTRA + 64 + c*64 + f] = (pa+pb)+(pc+pd);
  }
  __syncthreads();
  if (tid < 64) {
    float pool = 0.f;
#pragma unroll
    for (int c = 0; c < 8; ++c) pool += lds[EXTRA + 64 + c*64 + tid];
    lds[EXTRA + tid] = pool;               // pooled[0..63]
  }
  __syncthreads();

  // ---- head MLP ----
  if (tid < 256) {                         // y1 = leaky(pooled @ Wh1 + bh1), 256 wide
    float acc = P.bh1[tid];
#pragma unroll 4
    for (int k = 0; k < 64; ++k) acc = fmaf(lds[EXTRA+k], P.Wh1[k*256 + tid], acc);
    lds[EXTRA + 576 + tid] = acc >= 0.f ? acc : 0.2f*acc;  // y1 @ EXTRA+576..831
  }
  __syncthreads();
  if (tid < 256) {                         // y2 = leaky(y1 @ Wh2 + bh2), 256 wide
    float acc = P.bh2[tid];
#pragma unroll 4
    for (int k = 0; k < 256; ++k) acc = fmaf(lds[EXTRA+576+k], P.Wh2[k*256 + tid], acc);
    lds[EXTRA + 64 + tid] = acc >= 0.f ? acc : 0.2f*acc;   // y2 @ EXTRA+64..319
  }
  __syncthreads();
  if (tid < 64) {                          // y3 = leaky(y2 @ Wh3 + bh3), 64 wide
    float acc = P.bh3[tid];
#pragma unroll 4
    for (int k = 0; k < 256; ++k) acc = fmaf(lds[EXTRA+64+k], P.Wh3[k*64 + tid], acc);
    lds[EXTRA + 384 + tid] = acc >= 0.f ? acc : 0.2f*acc;
  }
  __syncthreads();
  if (tid == 0) {                          // out[g] = y3 @ Wh4 + bh4
    float acc = P.bh4[0];
#pragma unroll 4
    for (int k = 0; k < 64; ++k) acc = fmaf(lds[EXTRA+384+k], P.Wh4[k], acc);
    P.out[g] = acc;
  }
}

extern "C" void kernel_launch(void* const* d_in, const int* in_sizes, int n_in,
                              void* d_out, int out_size, void* d_ws, size_t ws_size,
                              hipStream_t stream) {
  Params P;
  P.x   = (const float*)d_in[0];
  P.W1  = (const float*)d_in[1];  P.b1  = (const float*)d_in[2];  P.a1 = (const float*)d_in[3];
  P.W2  = (const float*)d_in[4];  P.b2  = (const float*)d_in[5];  P.a2 = (const float*)d_in[6];
  P.Wc0 = (const float*)d_in[7];  P.bc0 = (const float*)d_in[8];
  P.Wc1 = (const float*)d_in[9];  P.bc1 = (const float*)d_in[10];
  P.Wc2 = (const float*)d_in[11]; P.bc2 = (const float*)d_in[12];
  P.Wc3 = (const float*)d_in[13]; P.bc3 = (const float*)d_in[14];
  P.W3  = (const float*)d_in[15]; P.b3  = (const float*)d_in[16]; P.a3 = (const float*)d_in[17];
  P.W4  = (const float*)d_in[18]; P.b4  = (const float*)d_in[19]; P.a4 = (const float*)d_in[20];
  P.Wh1 = (const float*)d_in[21]; P.bh1 = (const float*)d_in[22];
  P.Wh2 = (const float*)d_in[23]; P.bh2 = (const float*)d_in[24];
  P.Wh3 = (const float*)d_in[25]; P.bh3 = (const float*)d_in[26];
  P.Wh4 = (const float*)d_in[27]; P.bh4 = (const float*)d_in[28];
  P.out = (float*)d_out;

  (void)hipFuncSetAttribute(reinterpret_cast<const void*>(fused_gnn),
                            hipFuncAttributeMaxDynamicSharedMemorySize, LDS_BYTES);

  fused_gnn<<<NGRAPH, NT, LDS_BYTES, stream>>>(P);
}

// Round 6
// 785.028 us; speedup vs baseline: 1.1352x; 1.1352x over previous
//
#include <hip/hip_runtime.h>

#define NGRAPH 256
#define NNODE  512
#define KNN    6
#define NCAND  12
#define NF     64
#define ST     68                  // fp32 row stride (floats), 272B (16B-aligned)
#define SBF    72                  // bf16 row stride (shorts), 144B (16B-aligned)
#define TBS    20                  // filter tile buffer row stride (floats)
#define NT     512
// filter-phase layout (lives INSIDE the X region, dead after filter):
#define SQF    18432               // xbf = 512*72 shorts = 18432 floats at [0,18432)
#define TB0    18944               // 8 waves x 16x20 = 2560 floats
// persistent scratch above X region:
#define SCR    (NNODE*ST)          // 34816
#define CANDF  SCR                 // cand: 512*12 ushort = 12288B = 3072 floats
#define SQX    (SCR + 3072)        // exact fp32 sq, 512 floats
#define LDS_FLOATS (SCR + 3584)    // 38400 floats
#define LDS_BYTES  (LDS_FLOATS*4)  // 153600 B < 160 KiB
#define BIG 1e30f

typedef float v4f __attribute__((ext_vector_type(4)));
typedef short v8s __attribute__((ext_vector_type(8)));

struct Params {
  const float *x;
  const float *W1,*b1,*a1, *W2,*b2,*a2;
  const float *Wc0,*bc0, *Wc1,*bc1, *Wc2,*bc2, *Wc3,*bc3;
  const float *W3,*b3,*a3, *W4,*b4,*a4;
  const float *Wh1,*bh1, *Wh2,*bh2, *Wh3,*bh3, *Wh4,*bh4;
  float *out;
};

// fp32 -> bf16 (RNE) as raw ushort
__device__ __forceinline__ unsigned f2bf(float x) {
  union { float f; unsigned u; } cc; cc.f = x;
  unsigned u = cc.u;
  return (u + 0x7FFFu + ((u >> 16) & 1u)) >> 16;
}

// bf16 fragment: 8 consecutive bf16 from xbf row (16B-aligned)
__device__ __forceinline__ v8s bfrag(const unsigned short* xbf, int row, int c0) {
  return *(const v8s*)(xbf + row*SBF + c0);
}

// 64-feature row GEMM: acc[o] = sum_k row[k]*W[k*64+o] (W wave-uniform)
__device__ __forceinline__ void gemm64(const float* row, const float* W, float* acc) {
#pragma unroll
  for (int o = 0; o < NF; ++o) acc[o] = 0.f;
#pragma unroll 1
  for (int k4 = 0; k4 < 16; ++k4) {
    float4 xv = *(const float4*)(row + 4*k4);
    const float* w = W + 4*k4*NF;
#pragma unroll
    for (int o = 0; o < NF; ++o) acc[o] = fmaf(xv.x, w[o],        acc[o]);
#pragma unroll
    for (int o = 0; o < NF; ++o) acc[o] = fmaf(xv.y, w[NF+o],     acc[o]);
#pragma unroll
    for (int o = 0; o < NF; ++o) acc[o] = fmaf(xv.z, w[2*NF+o],   acc[o]);
#pragma unroll
    for (int o = 0; o < NF; ++o) acc[o] = fmaf(xv.w, w[3*NF+o],   acc[o]);
  }
}

__device__ __forceinline__ void linear_row(float* lds, int r, const float* W,
                                           const float* b, const float* a) {
  float acc[NF];
  float* row = lds + r*ST;
  gemm64(row, W, acc);
#pragma unroll
  for (int o4 = 0; o4 < 16; ++o4) {
    float t0 = acc[4*o4+0] + b[4*o4+0];
    float t1 = acc[4*o4+1] + b[4*o4+1];
    float t2 = acc[4*o4+2] + b[4*o4+2];
    float t3 = acc[4*o4+3] + b[4*o4+3];
    float4 v;
    v.x = t0 >= 0.f ? t0 : a[4*o4+0]*t0;
    v.y = t1 >= 0.f ? t1 : a[4*o4+1]*t1;
    v.z = t2 >= 0.f ? t2 : a[4*o4+2]*t2;
    v.w = t3 >= 0.f ? t3 : a[4*o4+3]*t3;
    *(float4*)(row + 4*o4) = v;
  }
}

// sorted-ascending top-8 insert; strict <
__device__ __forceinline__ void insert8(float (&b)[8], int (&bi)[8], float v, int vi) {
  if (v < b[7]) {
#pragma unroll
    for (int p = 0; p < 8; ++p) {
      bool lt = v < b[p];
      float tb = b[p]; int ti = bi[p];
      b[p]  = lt ? v  : tb;  bi[p] = lt ? vi : ti;
      v     = lt ? tb : v;   vi    = lt ? ti : vi;
    }
  }
}

// sorted-ascending top-12 insert; strict <
__device__ __forceinline__ void insert12(float (&b)[NCAND], int (&bi)[NCAND], float v, int vi) {
  if (v < b[NCAND-1]) {
#pragma unroll
    for (int p = 0; p < NCAND; ++p) {
      bool lt = v < b[p];
      float tb = b[p]; int ti = bi[p];
      b[p]  = lt ? v  : tb;  bi[p] = lt ? vi : ti;
      v     = lt ? tb : v;   vi    = lt ? ti : vi;
    }
  }
}

__global__ __launch_bounds__(NT, 2) void fused_gnn(Params P) {
  extern __shared__ float lds[];
  unsigned short* xbf  = (unsigned short*)lds;
  unsigned short* candU = (unsigned short*)&lds[CANDF];
  const int tid = threadIdx.x;
  const int g   = blockIdx.x;
  const int rA  = tid;

  const float4* xg = (const float4*)(P.x + (size_t)g * NNODE * NF);

  // ---- stage x[g] as bf16 into xbf (coalesced reads, 8B LDS stores) ----
#pragma unroll 1
  for (int i = tid; i < NNODE*NF/4; i += NT) {
    float4 v = xg[i];
    int row = i >> 4, k4 = i & 15;
    unsigned lo = f2bf(v.x) | (f2bf(v.y) << 16);
    unsigned hi = f2bf(v.z) | (f2bf(v.w) << 16);
    uint2 pk = {lo, hi};
    *(uint2*)&xbf[row*SBF + 4*k4] = pk;
  }
  __syncthreads();

  // ---- filter sq (from bf16 values — consistent with MFMA dot) ----
  {
    const unsigned* xr32 = (const unsigned*)(xbf + rA*SBF);
    float s = 0.f;
#pragma unroll
    for (int k = 0; k < 32; ++k) {
      unsigned u = xr32[k];
      union { unsigned u; float f; } c0, c1;
      c0.u = u << 16; c1.u = u & 0xffff0000u;
      s = fmaf(c0.f, c0.f, s);
      s = fmaf(c1.f, c1.f, s);
    }
    lds[SQF + rA] = s;
  }
  __syncthreads();

  // ==== kNN filter: bf16 MFMA Gram + per-wave tile transpose + lane-local top-8 ====
  {
    const int lane = tid & 63;
    const int w    = tid >> 6;          // wave 0..7
    const int c    = lane & 15;
    const int qq   = lane >> 4;         // 0..3
    float* tb = &lds[TB0 + w*16*TBS];   // per-wave 16x20 tile buffer

#pragma unroll 1
    for (int p = 0; p < 4; ++p) {
      const int i0 = (p*8 + w) * 16;
      v8s A0 = bfrag(xbf, i0 + c, qq*8);
      v8s A1 = bfrag(xbf, i0 + c, 32 + qq*8);
      const int myrow = i0 + c;         // reader-role row (lane&15 == c)

      float d8[8]; int i8[8];
#pragma unroll
      for (int m = 0; m < 8; ++m) { d8[m] = BIG; i8[m] = 0; }

#pragma unroll 1
      for (int jt = 0; jt < 32; ++jt) {
        const int j0 = jt * 16;
        v8s B0 = bfrag(xbf, j0 + c, qq*8);
        v8s B1 = bfrag(xbf, j0 + c, 32 + qq*8);
        v4f acc = {0.f, 0.f, 0.f, 0.f};
        acc = __builtin_amdgcn_mfma_f32_16x16x32_bf16(A0, B0, acc, 0, 0, 0);
        acc = __builtin_amdgcn_mfma_f32_16x16x32_bf16(A1, B1, acc, 0, 0, 0);
        // write C tile: row_local = qq*4+r (i), col_local = c (j)
#pragma unroll
        for (int r = 0; r < 4; ++r) tb[(qq*4 + r)*TBS + c] = acc[r];
        // read back own row's 4 cols (intra-wave RAW; compiler emits lgkmcnt)
        float4 dv = *(const float4*)&tb[c*TBS + qq*4];
        float4 sv = *(const float4*)&lds[SQF + j0 + qq*4];
        float e0 = fmaf(-2.f, dv.x, sv.x);
        float e1 = fmaf(-2.f, dv.y, sv.y);
        float e2 = fmaf(-2.f, dv.z, sv.z);
        float e3 = fmaf(-2.f, dv.w, sv.w);
        const int jb = j0 + qq*4;
        if (jb     == myrow) e0 = BIG;
        if (jb + 1 == myrow) e1 = BIG;
        if (jb + 2 == myrow) e2 = BIG;
        if (jb + 3 == myrow) e3 = BIG;
        insert8(d8, i8, e0, jb);
        insert8(d8, i8, e1, jb+1);
        insert8(d8, i8, e2, jb+2);
        insert8(d8, i8, e3, jb+3);
      }

      // merge across the 4 qq-lanes sharing this row: 2 butterfly stages
      float cd[NCAND]; int ci[NCAND];
#pragma unroll
      for (int m = 0; m < 8; ++m) { cd[m] = d8[m]; ci[m] = i8[m]; }
#pragma unroll
      for (int m = 8; m < NCAND; ++m) { cd[m] = BIG; ci[m] = 0; }
      {
        float pd[8]; int pi[8];
#pragma unroll
        for (int s = 0; s < 8; ++s) { pd[s] = __shfl_xor(cd[s], 16); pi[s] = __shfl_xor(ci[s], 16); }
#pragma unroll
        for (int s = 0; s < 8; ++s) insert12(cd, ci, pd[s], pi[s]);
      }
      {
        float pd[NCAND]; int pi[NCAND];
#pragma unroll
        for (int s = 0; s < NCAND; ++s) { pd[s] = __shfl_xor(cd[s], 32); pi[s] = __shfl_xor(ci[s], 32); }
#pragma unroll
        for (int s = 0; s < NCAND; ++s) insert12(cd, ci, pd[s], pi[s]);
      }
      if (lane < 16) {
#pragma unroll
        for (int s = 0; s < NCAND; ++s) candU[(i0 + lane)*NCAND + s] = (unsigned short)ci[s];
      }
    }
  }
  __syncthreads();

  // ---- restage fp32 X (L2/L3-warm re-read), overwrites xbf/sqf/tilebuf ----
#pragma unroll 1
  for (int i = tid; i < NNODE*NF/4; i += NT) {
    float4 v = xg[i];
    int row = i >> 4, k4 = i & 15;
    *(float4*)&lds[row*ST + 4*k4] = v;
  }
  __syncthreads();

  // ---- exact fp32 sq ----
  {
    float s0 = 0.f;
#pragma unroll
    for (int k4 = 0; k4 < 16; ++k4) {
      float4 a = *(const float4*)&lds[rA*ST + 4*k4];
      s0 = fmaf(a.x,a.x,s0); s0 = fmaf(a.y,a.y,s0); s0 = fmaf(a.z,a.z,s0); s0 = fmaf(a.w,a.w,s0);
    }
    lds[SQX + rA] = s0;
  }
  __syncthreads();

  // ==== exact fp32 re-rank of 12 candidates (R3-identical math) ====
  int nbrA[KNN];
  {
    float4 xr16[16];
#pragma unroll
    for (int k4 = 0; k4 < 16; ++k4)
      xr16[k4] = *(const float4*)&lds[rA*ST + 4*k4];

    float nd[6]; int ni[6];
#pragma unroll
    for (int m = 0; m < 6; ++m) { nd[m] = BIG; ni[m] = 0x7fffffff; }

    int cnd[NCAND];
#pragma unroll
    for (int s = 0; s < NCAND; ++s) cnd[s] = candU[rA*NCAND + s];

#pragma unroll 1
    for (int s = 0; s < NCAND; ++s) {
      int j = cnd[s];
      const float* xj = &lds[j*ST];
      float4 aa = {0.f, 0.f, 0.f, 0.f};
#pragma unroll
      for (int k4 = 0; k4 < 16; ++k4) {
        float4 v = *(const float4*)(xj + 4*k4);
        aa.x = fmaf(xr16[k4].x, v.x, aa.x); aa.y = fmaf(xr16[k4].y, v.y, aa.y);
        aa.z = fmaf(xr16[k4].z, v.z, aa.z); aa.w = fmaf(xr16[k4].w, v.w, aa.w);
      }
      float e = fmaf(-2.f, (aa.x+aa.y)+(aa.z+aa.w), lds[SQX + j]);
      if (e < nd[5] || (e == nd[5] && j < ni[5])) {
#pragma unroll
        for (int pp = 0; pp < 6; ++pp) {
          bool lt = (e < nd[pp]) || (e == nd[pp] && j < ni[pp]);
          float tb = nd[pp]; int ti = ni[pp];
          nd[pp] = lt ? e : tb;  ni[pp] = lt ? j : ti;
          e      = lt ? tb : e;  j      = lt ? ti : j;
        }
      }
    }
#pragma unroll
    for (int m = 0; m < 6; ++m) nbrA[m] = ni[m];
  }
  __syncthreads();   // refine reads (random rows) done before layers overwrite

  // ---- h = prelu(x@W1+b1); h = prelu(h@W2+b2) ----
  linear_row(lds, rA, P.W1, P.b1, P.a1);
  linear_row(lds, rA, P.W2, P.b2, P.a2);

  // ---- 4x gconv ----
  const float* Wcs[4] = {P.Wc0, P.Wc1, P.Wc2, P.Wc3};
  const float* bcs[4] = {P.bc0, P.bc1, P.bc2, P.bc3};
#pragma unroll 1
  for (int cv = 0; cv < 4; ++cv) {
    const float* W = Wcs[cv];
    const float* b = bcs[cv];
    float hsA[NF];
#pragma unroll
    for (int k4 = 0; k4 < 16; ++k4) {
      float4 v = *(const float4*)&lds[rA*ST + 4*k4];
      hsA[4*k4]=v.x; hsA[4*k4+1]=v.y; hsA[4*k4+2]=v.z; hsA[4*k4+3]=v.w;
    }
    {
      float p0[NF];
      gemm64(&lds[rA*ST], W, p0);
#pragma unroll
      for (int o4 = 0; o4 < 16; ++o4) {
        float4 v = {p0[4*o4], p0[4*o4+1], p0[4*o4+2], p0[4*o4+3]};
        *(float4*)&lds[rA*ST + 4*o4] = v;
      }
    }
    __syncthreads();                       // all p-rows published
    float sA[NF];
    {
      const float* pr = &lds[nbrA[0]*ST];
#pragma unroll
      for (int o4 = 0; o4 < 16; ++o4) {
        float4 v = *(const float4*)(pr + 4*o4);
        sA[4*o4]=v.x; sA[4*o4+1]=v.y; sA[4*o4+2]=v.z; sA[4*o4+3]=v.w;
      }
    }
#pragma unroll
    for (int m = 1; m < KNN; ++m) {
      const float* pr = &lds[nbrA[m]*ST];
#pragma unroll
      for (int o4 = 0; o4 < 16; ++o4) {
        float4 v = *(const float4*)(pr + 4*o4);
        sA[4*o4]+=v.x; sA[4*o4+1]+=v.y; sA[4*o4+2]+=v.z; sA[4*o4+3]+=v.w;
      }
    }
    __syncthreads();                       // gathers done before overwrite
#pragma unroll
    for (int o4 = 0; o4 < 16; ++o4) {
      float4 v;
      v.x = sA[4*o4]   + 6.f*b[4*o4]   + hsA[4*o4];
      v.y = sA[4*o4+1] + 6.f*b[4*o4+1] + hsA[4*o4+1];
      v.z = sA[4*o4+2] + 6.f*b[4*o4+2] + hsA[4*o4+2];
      v.w = sA[4*o4+3] + 6.f*b[4*o4+3] + hsA[4*o4+3];
      *(float4*)&lds[rA*ST + 4*o4] = v;
    }
  }

  // ---- last two PReLU linears ----
  linear_row(lds, rA, P.W3, P.b3, P.a3);
  linear_row(lds, rA, P.W4, P.b4, P.a4);

  __syncthreads();

  // ---- global add pool ----
  {
    int f = tid & 63, c = tid >> 6;
    int rstart = c * 64;
    float pa=0.f, pb=0.f, pc=0.f, pd=0.f;
#pragma unroll 1
    for (int r = 0; r < 64; r += 4) {
      pa += lds[(rstart+r  )*ST + f];
      pb += lds[(rstart+r+1)*ST + f];
      pc += lds[(rstart+r+2)*ST + f];
      pd += lds[(rstart+r+3)*ST + f];
    }
    lds[SCR + c*64 + f] = (pa+pb)+(pc+pd);
  }
  __syncthreads();
  if (tid < 64) {
    float pool = 0.f;
#pragma unroll
    for (int c = 0; c < 8; ++c) pool += lds[SCR + c*64 + tid];
    lds[SCR + 512 + tid] = pool;           // pooled[0..63]
  }
  __syncthreads();

  // ---- head MLP ----
  if (tid < 256) {
    float acc = P.bh1[tid];
#pragma unroll 4
    for (int k = 0; k < 64; ++k) acc = fmaf(lds[SCR+512+k], P.Wh1[k*256 + tid], acc);
    lds[SCR + 576 + tid] = acc >= 0.f ? acc : 0.2f*acc;
  }
  __syncthreads();
  if (tid < 256) {
    float acc = P.bh2[tid];
#pragma unroll 4
    for (int k = 0; k < 256; ++k) acc = fmaf(lds[SCR+576+k], P.Wh2[k*256 + tid], acc);
    lds[SCR + 832 + tid] = acc >= 0.f ? acc : 0.2f*acc;
  }
  __syncthreads();
  if (tid < 64) {
    float acc = P.bh3[tid];
#pragma unroll 4
    for (int k = 0; k < 256; ++k) acc = fmaf(lds[SCR+832+k], P.Wh3[k*64 + tid], acc);
    lds[SCR + 1088 + tid] = acc >= 0.f ? acc : 0.2f*acc;
  }
  __syncthreads();
  if (tid == 0) {
    float acc = P.bh4[0];
#pragma unroll 4
    for (int k = 0; k < 64; ++k) acc = fmaf(lds[SCR+1088+k], P.Wh4[k], acc);
    P.out[g] = acc;
  }
}

extern "C" void kernel_launch(void* const* d_in, const int* in_sizes, int n_in,
                              void* d_out, int out_size, void* d_ws, size_t ws_size,
                              hipStream_t stream) {
  Params P;
  P.x   = (const float*)d_in[0];
  P.W1  = (const float*)d_in[1];  P.b1  = (const float*)d_in[2];  P.a1 = (const float*)d_in[3];
  P.W2  = (const float*)d_in[4];  P.b2  = (const float*)d_in[5];  P.a2 = (const float*)d_in[6];
  P.Wc0 = (const float*)d_in[7];  P.bc0 = (const float*)d_in[8];
  P.Wc1 = (const float*)d_in[9];  P.bc1 = (const float*)d_in[10];
  P.Wc2 = (const float*)d_in[11]; P.bc2 = (const float*)d_in[12];
  P.Wc3 = (const float*)d_in[13]; P.bc3 = (const float*)d_in[14];
  P.W3  = (const float*)d_in[15]; P.b3  = (const float*)d_in[16]; P.a3 = (const float*)d_in[17];
  P.W4  = (const float*)d_in[18]; P.b4  = (const float*)d_in[19]; P.a4 = (const float*)d_in[20];
  P.Wh1 = (const float*)d_in[21]; P.bh1 = (const float*)d_in[22];
  P.Wh2 = (const float*)d_in[23]; P.bh2 = (const float*)d_in[24];
  P.Wh3 = (const float*)d_in[25]; P.bh3 = (const float*)d_in[26];
  P.Wh4 = (const float*)d_in[27]; P.bh4 = (const float*)d_in[28];
  P.out = (float*)d_out;

  (void)hipFuncSetAttribute(reinterpret_cast<const void*>(fused_gnn),
                            hipFuncAttributeMaxDynamicSharedMemorySize, LDS_BYTES);

  fused_gnn<<<NGRAPH, NT, LDS_BYTES, stream>>>(P);
}